// Round 13
// baseline (266.791 us; speedup 1.0000x reference)
//
#include <hip/hip_runtime.h>
#include <hip/hip_bf16.h>
#include <math.h>

constexpr int R_ = 4096;

typedef __attribute__((ext_vector_type(8))) short short8;
typedef __attribute__((ext_vector_type(4))) float f32x4;
typedef __attribute__((ext_vector_type(16))) float f32x16;
typedef __attribute__((ext_vector_type(2))) unsigned int uint2v;

#define MFMA32(a, b, c) __builtin_amdgcn_mfma_f32_32x32x16_bf16(a, b, c, 0, 0, 0)

union U4 { unsigned int u[4]; short8 s8; };

__device__ __forceinline__ unsigned short f2bf(float f) {
    unsigned int u = __float_as_uint(f);
    u += 0x7fffu + ((u >> 16) & 1u);   // RNE
    return (unsigned short)(u >> 16);
}

__device__ __forceinline__ unsigned int cvtpk(float lo, float hi) {
    unsigned int d;
    asm("v_cvt_pk_bf16_f32 %0, %1, %2" : "=v"(d) : "v"(lo), "v"(hi));
    return d;
}
// builtin (not raw asm): hazard recognizer must see permlane (round-5 lesson)
__device__ __forceinline__ void swap32(unsigned int& a, unsigned int& b) {
    uint2v r = __builtin_amdgcn_permlane32_swap(a, b, false, false);
    a = r[0]; b = r[1];
}

__device__ __forceinline__ short8 pack_half(float a0, float a1, float a2, float a3,
                                            float b0, float b1, float b2, float b3) {
    unsigned int x0 = cvtpk(a0, a1), x1 = cvtpk(a2, a3);
    unsigned int x2 = cvtpk(b0, b1), x3 = cvtpk(b2, b3);
    swap32(x0, x2);
    swap32(x1, x3);
    U4 t; t.u[0] = x0; t.u[1] = x1; t.u[2] = x2; t.u[3] = x3;
    return t.s8;
}

// ---------------------------------------------------------------------------
// Weight prep (UNCHANGED): bf16 fragments in MFMA order.
//   dst elem = base + ((ct*KS + ks)*64 + lane)*8 + j,  n = ct*32+ls,
//   k = ks*16 + hi*8 + j.  Regions: L0 @0 (KS=4), L1 @16384, L2 @81920,
//   Wc1 @147456 (all KS=16).
// ---------------------------------------------------------------------------
__global__ __launch_bounds__(256) void prep_weights(
    const float* __restrict__ W0, const float* __restrict__ W1,
    const float* __restrict__ W2, const float* __restrict__ Wc1,
    unsigned short* __restrict__ out)
{
    int i = blockIdx.x * 256 + threadIdx.x;
    if (i >= 180224) return;
    float val;
    if (i < 16384) {
        int j = i & 7, l = (i >> 3) & 63, q = i >> 9;
        int ks = q & 3, ct = q >> 2, ls = l & 31, hi = l >> 5;
        int n = ct * 32 + ls, k = ks * 16 + hi * 8 + j;
        val = (k < 63) ? W0[k * 256 + n] : 0.f;
    } else if (i < 81920) {
        int e = i - 16384;
        int j = e & 7, l = (e >> 3) & 63, q = e >> 9;
        int ks = q & 15, ct = q >> 4, ls = l & 31, hi = l >> 5;
        int n = ct * 32 + ls, k = ks * 16 + hi * 8 + j;
        val = W1[k * 256 + n];
    } else if (i < 147456) {
        int e = i - 81920;
        int j = e & 7, l = (e >> 3) & 63, q = e >> 9;
        int ks = q & 15, ct = q >> 4, ls = l & 31, hi = l >> 5;
        int n = ct * 32 + ls, k = ks * 16 + hi * 8 + j;
        val = W2[k * 256 + n];
    } else {
        int e = i - 147456;
        int j = e & 7, l = (e >> 3) & 63, q = e >> 9;
        int ks = q & 15, ct = q >> 4, ls = l & 31, hi = l >> 5;
        int n = ct * 32 + ls, k = ks * 16 + hi * 8 + j;
        val = Wc1[k * 128 + n];
    }
    out[i] = f2bf(val);
}

// Per-tile epilogue (identical math to green rounds 6/9/10/12).
template <bool DO_SIGMA, bool DO_PACK, bool DO_COLOR>
__device__ __forceinline__ void epilog(
    const f32x16& acc, int ct,
    const float* __restrict__ wsv, const float* __restrict__ wc2R,
    int hi, short8* __restrict__ Bout,
    float& sp, float& c0, float& c1, float& c2)
{
    float rr[16];
    #pragma unroll
    for (int i = 0; i < 16; ++i) rr[i] = fmaxf(acc[i], 0.f);
    if constexpr (DO_SIGMA) {
        #pragma unroll
        for (int g = 0; g < 4; ++g) {
            f32x4 wv = *(const f32x4*)&wsv[ct * 32 + 4 * hi + 8 * g];
            sp = fmaf(rr[4*g+0], wv[0], sp);
            sp = fmaf(rr[4*g+1], wv[1], sp);
            sp = fmaf(rr[4*g+2], wv[2], sp);
            sp = fmaf(rr[4*g+3], wv[3], sp);
        }
    }
    if constexpr (DO_COLOR) {
        #pragma unroll
        for (int g = 0; g < 4; ++g) {
            int nb = ct * 32 + 4 * hi + 8 * g;
            f32x4 w0 = *(const f32x4*)&wc2R[0 * 128 + nb];
            f32x4 w1 = *(const f32x4*)&wc2R[1 * 128 + nb];
            f32x4 w2 = *(const f32x4*)&wc2R[2 * 128 + nb];
            #pragma unroll
            for (int i = 0; i < 4; ++i) {
                c0 = fmaf(rr[4*g+i], w0[i], c0);
                c1 = fmaf(rr[4*g+i], w1[i], c1);
                c2 = fmaf(rr[4*g+i], w2[i], c2);
            }
        }
    }
    if constexpr (DO_PACK) {
        Bout[2*ct+0] = pack_half(rr[0], rr[1], rr[2],  rr[3],
                                 rr[4], rr[5], rr[6],  rr[7]);
        Bout[2*ct+1] = pack_half(rr[8], rr[9], rr[10], rr[11],
                                 rr[12], rr[13], rr[14], rr[15]);
    }
}

// One K=256 layer; rolling 4-fragment window + per-tile __syncthreads()
// (all 8 waves stream the same 16 KB tile through L1 together).
template <int NT, bool DO_SIGMA, bool DO_PACK, bool DO_COLOR>
__device__ __forceinline__ void mlp_layer(
    const unsigned short* __restrict__ wbase,
    const float* __restrict__ biasv,
    const float* __restrict__ wsv,
    const float* __restrict__ wc2R,
    int lane, int hi,
    const short8 (&Bin)[16], short8* __restrict__ Bout,
    float& sp, float& c0, float& c1, float& c2)
{
    const short8* __restrict__ w = (const short8*)wbase + lane;
    short8 A[4], B4[4];
    #pragma unroll
    for (int j = 0; j < 4; ++j) A[j] = w[j * 64];            // tile0 ks0-3
    #pragma unroll
    for (int ct = 0; ct < NT; ++ct) {
        f32x16 acc;
        #pragma unroll
        for (int g = 0; g < 4; ++g) {
            f32x4 bv = *(const f32x4*)&biasv[ct * 32 + 4 * hi + 8 * g];
            acc[4*g+0]=bv[0]; acc[4*g+1]=bv[1]; acc[4*g+2]=bv[2]; acc[4*g+3]=bv[3];
        }
        #pragma unroll
        for (int j = 0; j < 4; ++j) B4[j] = w[(ct * 16 + 4 + j) * 64];
        #pragma unroll
        for (int j = 0; j < 4; ++j) acc = MFMA32(A[j], Bin[j], acc);
        #pragma unroll
        for (int j = 0; j < 4; ++j) A[j] = w[(ct * 16 + 8 + j) * 64];
        #pragma unroll
        for (int j = 0; j < 4; ++j) acc = MFMA32(B4[j], Bin[4 + j], acc);
        #pragma unroll
        for (int j = 0; j < 4; ++j) B4[j] = w[(ct * 16 + 12 + j) * 64];
        #pragma unroll
        for (int j = 0; j < 4; ++j) acc = MFMA32(A[j], Bin[8 + j], acc);
        if (ct + 1 < NT) {
            #pragma unroll
            for (int j = 0; j < 4; ++j) A[j] = w[((ct + 1) * 16 + j) * 64];
        }
        #pragma unroll
        for (int j = 0; j < 4; ++j) acc = MFMA32(B4[j], Bin[12 + j], acc);
        epilog<DO_SIGMA, DO_PACK, DO_COLOR>(acc, ct, wsv, wc2R, hi, Bout,
                                            sp, c0, c1, c2);
        __syncthreads();   // wave-align for L1 reuse of the weight stream
    }
}

// ---------------------------------------------------------------------------
// Fused NeRF: 1 block = 2 RAYS, 512 threads = 8 waves.
// Wave wv: rh = wv>>2 selects the ray, lw = wv&3 owns 32 samples of it.
// Per-wave math identical to green r12; all 8 waves share the weight stream.
// ---------------------------------------------------------------------------
__global__ __launch_bounds__(512, 2) void nerf_kernel(
    const float* __restrict__ ray, const float* __restrict__ t,
    const float* __restrict__ b0g, const float* __restrict__ b1g,
    const float* __restrict__ b2g,
    const float* __restrict__ Wsg, const float* __restrict__ bsg,
    const float* __restrict__ Wc1g, const float* __restrict__ bc1g,
    const float* __restrict__ Wc2g, const float* __restrict__ bc2g,
    const unsigned short* __restrict__ wt,
    float* __restrict__ rgb_out, float* __restrict__ wi_out)
{
    __shared__ __align__(16) unsigned char s_xe[2][128 * 128];  // 32 KB posenc
    __shared__ __align__(16) float s_bias[768];     // b0|b1|b2 (ray-shared)
    __shared__ __align__(16) float s_decont[2][128];
    __shared__ __align__(16) float s_ws[256];
    __shared__ __align__(16) float s_wc2R[384];     // [c][128]
    __shared__ float s_sigma[2][128];
    __shared__ float s_color[2][384];
    __shared__ float s_de[2][27];
    __shared__ float s_od[2][6];
    __shared__ float s_t[2][129];
    __shared__ float s_ts[2][129];
    __shared__ float s_sdt[2][128];
    __shared__ float s_cum[2][128];
    __shared__ float s_wi[2][128];

    const int tid  = threadIdx.x;
    const int rh   = tid >> 8;          // ray half (0/1)
    const int t2   = tid & 255;         // thread index within the ray
    const int wv   = tid >> 6;
    const int lane = tid & 63;
    const int ls   = lane & 31;
    const int hi   = lane >> 5;
    const int lw   = wv & 3;            // wave within ray
    const int row  = lw * 32 + ls;      // this lane's sample within the ray
    const int sw   = (ls & 7) << 4;
    const int r    = blockIdx.x * 2 + rh;

    if (tid < 12) s_od[tid / 6][tid % 6] = ray[(blockIdx.x * 2 + tid / 6) * 6 + tid % 6];
    __syncthreads();
    const float d0 = s_od[rh][3], d1 = s_od[rh][4], d2 = s_od[rh][5];

    // ---- fills: biases, head weights, de, t ----
    s_bias[tid < 256 ? tid : tid] = 0.f;   // placeholder overwritten below
    s_bias[tid] = (tid < 256) ? b0g[tid] : b1g[tid - 256];   // 0..511
    if (tid < 256) s_bias[512 + tid] = b2g[tid];
    if (tid < 256) s_ws[tid] = Wsg[tid];
    if (tid < 384) {
        int c = tid >> 7, n = tid & 127;
        s_wc2R[tid] = Wc2g[n * 3 + c];
    }
    if (t2 < 129) s_t[rh][t2] = t[r * 129 + t2];
    if (t2 < 27) {
        int f = t2; float v;
        if (f < 3) v = (f == 0) ? d0 : ((f == 1) ? d1 : d2);
        else {
            int q = f - 3, l = q / 6, rm = q % 6, c = rm % 3;
            float dc = (c == 0) ? d0 : ((c == 1) ? d1 : d2);
            float a = dc * (float)(1 << l);
            v = (rm < 3) ? sinf(a) : cosf(a);
        }
        s_de[rh][f] = v;
    }
    __syncthreads();

    // ---- posenc(x,10) into s_xe[rh] (rows=sample, 64 bf16, XOR-swizzled) --
    {
        const int p = t2 & 127;
        const int psw = (p & 7) << 4;
        unsigned char* xp = s_xe[rh] + p * 128;
        float tv = t[r * 129 + 1 + p];
        if (t2 < 128) {
            #pragma unroll
            for (int cgi = 0; cgi < 2; ++cgi) {
                float x = s_od[rh][cgi] + tv * s_od[rh][cgi + 3];
                *(unsigned short*)(xp + ((2 * cgi) ^ psw)) = f2bf(x);
                float sv = sinf(x), cv = cosf(x);
                #pragma unroll
                for (int l = 0; l < 10; ++l) {
                    *(unsigned short*)(xp + ((2 * (3 + 6 * l + cgi)) ^ psw)) = f2bf(sv);
                    *(unsigned short*)(xp + ((2 * (6 + 6 * l + cgi)) ^ psw)) = f2bf(cv);
                    float ns = 2.f * sv * cv, nc = 1.f - 2.f * sv * sv;
                    sv = ns; cv = nc;
                }
            }
        } else {
            float x = s_od[rh][2] + tv * s_od[rh][5];
            *(unsigned short*)(xp + (4 ^ psw)) = f2bf(x);
            float sv = sinf(x), cv = cosf(x);
            #pragma unroll
            for (int l = 0; l < 10; ++l) {
                *(unsigned short*)(xp + ((2 * (5 + 6 * l)) ^ psw)) = f2bf(sv);
                *(unsigned short*)(xp + ((2 * (8 + 6 * l)) ^ psw)) = f2bf(cv);
                float ns = 2.f * sv * cv, nc = 1.f - 2.f * sv * sv;
                sv = ns; cv = nc;
            }
            *(unsigned short*)(xp + (126 ^ psw)) = 0;
            // decont[j] = bc1[j] + sum_k de[k]*Wc1[256+k][j]
            float acc = bc1g[p];
            for (int k = 0; k < 27; ++k)
                acc = fmaf(s_de[rh][k], Wc1g[(256 + k) * 128 + p], acc);
            s_decont[rh][p] = acc;
        }
    }
    __syncthreads();

    // ======================= MLP ===========================================
    short8 BA[16], BB[16];
    float sp = 0.f, c0 = 0.f, c1 = 0.f, c2 = 0.f;

    // Layer 0 (K=64): B from s_xe[rh], 8 tiles, 4-frag ping-pong -> BA
    {
        short8 BX[4];
        #pragma unroll
        for (int ks = 0; ks < 4; ++ks)
            BX[ks] = *(const short8*)(s_xe[rh] + row * 128 + ((32 * ks + 16 * hi) ^ sw));
        const short8* __restrict__ w0 = (const short8*)wt + lane;
        short8 Q0[4], Q1[4];
        #pragma unroll
        for (int j = 0; j < 4; ++j) Q0[j] = w0[j * 64];
        #pragma unroll
        for (int ct = 0; ct < 8; ++ct) {
            if (ct + 1 < 8) {
                #pragma unroll
                for (int j = 0; j < 4; ++j)
                    Q1[j] = w0[((ct + 1) * 4 + j) * 64];
            }
            f32x16 acc;
            #pragma unroll
            for (int g = 0; g < 4; ++g) {
                f32x4 bv = *(const f32x4*)&s_bias[ct * 32 + 4 * hi + 8 * g];
                acc[4*g+0]=bv[0]; acc[4*g+1]=bv[1]; acc[4*g+2]=bv[2]; acc[4*g+3]=bv[3];
            }
            #pragma unroll
            for (int j = 0; j < 4; ++j) acc = MFMA32(Q0[j], BX[j], acc);
            epilog<false, true, false>(acc, ct, nullptr, nullptr, hi, BA,
                                       sp, c0, c1, c2);
            #pragma unroll
            for (int j = 0; j < 4; ++j) Q0[j] = Q1[j];   // renamed, unrolled
        }
    }

    // Layer 1: BA -> BB
    mlp_layer<8, false, true, false>(wt + 16384, s_bias + 256, nullptr, nullptr,
                                     lane, hi, BA, BB, sp, c0, c1, c2);
    // Layer 2: BB -> BA, sigma partial accumulated
    mlp_layer<8, true, true, false>(wt + 81920, s_bias + 512, s_ws, nullptr,
                                    lane, hi, BB, BA, sp, c0, c1, c2);
    // sigma finalize
    sp += __shfl_xor(sp, 32);
    if (lane < 32) {
        float x = sp + bsg[0];
        s_sigma[rh][row] = fmaxf(x, 0.f) + log1pf(expf(-fabsf(x)));
    }
    // Wc1 (128 cols): BA -> color partials (per-ray decont bias)
    mlp_layer<4, false, false, true>(wt + 147456, s_decont[rh], nullptr, s_wc2R,
                                     lane, hi, BA, BB, sp, c0, c1, c2);
    c0 += __shfl_xor(c0, 32);
    c1 += __shfl_xor(c1, 32);
    c2 += __shfl_xor(c2, 32);
    if (lane < 32) {
        s_color[rh][row * 3 + 0] = 1.f / (1.f + expf(-(c0 + bc2g[0])));
        s_color[rh][row * 3 + 1] = 1.f / (1.f + expf(-(c1 + bc2g[1])));
        s_color[rh][row * 3 + 2] = 1.f / (1.f + expf(-(c2 + bc2g[2])));
    }
    __syncthreads();

    // ======================= render (sort/scan/composite) ==================
    if (t2 < 129) {
        float v = s_t[rh][t2];
        int rank = 0;
        for (int j = 0; j < 129; ++j) {
            float u = s_t[rh][j];
            rank += (u < v) || (u == v && j < t2);
        }
        s_ts[rh][rank] = v;
    }
    __syncthreads();
    if (t2 < 128) {
        float dt = s_ts[rh][t2 + 1] - s_ts[rh][t2];
        float sd = s_sigma[rh][t2] * dt;
        s_sdt[rh][t2] = sd;
        s_cum[rh][t2] = sd;
    }
    __syncthreads();
    for (int off = 1; off < 128; off <<= 1) {
        float add = (t2 < 128 && t2 >= off) ? s_cum[rh][t2 - off] : 0.f;
        __syncthreads();
        if (t2 < 128) s_cum[rh][t2] += add;
        __syncthreads();
    }
    if (t2 < 128) {
        float Ti = (t2 == 0) ? 1.f : expf(-s_cum[rh][t2 - 1]);
        float alpha = 1.f - expf(-s_sdt[rh][t2]);
        float w = Ti * alpha;
        s_wi[rh][t2] = w;
        wi_out[r * 128 + t2] = w;
    }
    __syncthreads();
    if (t2 < 3) {
        float acc = 0.f;
        for (int i = 0; i < 128; ++i)
            acc = fmaf(s_wi[rh][i], s_color[rh][i * 3 + t2], acc);
        rgb_out[r * 3 + t2] = acc;
    }
}

extern "C" void kernel_launch(void* const* d_in, const int* in_sizes, int n_in,
                              void* d_out, int out_size, void* d_ws, size_t ws_size,
                              hipStream_t stream)
{
    const float* ray = (const float*)d_in[0];
    const float* t   = (const float*)d_in[1];
    const float* W0  = (const float*)d_in[2];
    const float* b0  = (const float*)d_in[3];
    const float* W1  = (const float*)d_in[4];
    const float* b1  = (const float*)d_in[5];
    const float* W2  = (const float*)d_in[6];
    const float* b2  = (const float*)d_in[7];
    const float* Ws  = (const float*)d_in[8];
    const float* bs  = (const float*)d_in[9];
    const float* Wc1 = (const float*)d_in[10];
    const float* bc1 = (const float*)d_in[11];
    const float* Wc2 = (const float*)d_in[12];
    const float* bc2 = (const float*)d_in[13];

    unsigned short* wt = (unsigned short*)d_ws;   // 360448 B fragment image
    float* rgb_out = (float*)d_out;               // R*3
    float* wi_out  = rgb_out + R_ * 3;            // R*128

    hipLaunchKernelGGL(prep_weights, dim3(704), dim3(256), 0, stream,
                       W0, W1, W2, Wc1, wt);
    hipLaunchKernelGGL(nerf_kernel, dim3(R_ / 2), dim3(512), 0, stream,
                       ray, t, b0, b1, b2, Ws, bs, Wc1, bc1, Wc2, bc2,
                       wt, rgb_out, wi_out);
}

// Round 14
// 212.074 us; speedup vs baseline: 1.2580x; 1.2580x over previous
//
#include <hip/hip_runtime.h>
#include <hip/hip_bf16.h>
#include <math.h>

constexpr int R_ = 4096;

typedef __attribute__((ext_vector_type(8))) short short8;
typedef __attribute__((ext_vector_type(4))) float f32x4;
typedef __attribute__((ext_vector_type(16))) float f32x16;
typedef __attribute__((ext_vector_type(2))) unsigned int uint2v;

#define MFMA32(a, b, c) __builtin_amdgcn_mfma_f32_32x32x16_bf16(a, b, c, 0, 0, 0)

union U4 { unsigned int u[4]; short8 s8; };

__device__ __forceinline__ unsigned short f2bf(float f) {
    unsigned int u = __float_as_uint(f);
    u += 0x7fffu + ((u >> 16) & 1u);   // RNE
    return (unsigned short)(u >> 16);
}

__device__ __forceinline__ unsigned int cvtpk(float lo, float hi) {
    unsigned int d;
    asm("v_cvt_pk_bf16_f32 %0, %1, %2" : "=v"(d) : "v"(lo), "v"(hi));
    return d;
}
// builtin (not raw asm): hazard recognizer must see permlane (round-5 lesson)
__device__ __forceinline__ void swap32(unsigned int& a, unsigned int& b) {
    uint2v r = __builtin_amdgcn_permlane32_swap(a, b, false, false);
    a = r[0]; b = r[1];
}

__device__ __forceinline__ short8 pack_half(float a0, float a1, float a2, float a3,
                                            float b0, float b1, float b2, float b3) {
    unsigned int x0 = cvtpk(a0, a1), x1 = cvtpk(a2, a3);
    unsigned int x2 = cvtpk(b0, b1), x3 = cvtpk(b2, b3);
    swap32(x0, x2);
    swap32(x1, x3);
    U4 t; t.u[0] = x0; t.u[1] = x1; t.u[2] = x2; t.u[3] = x3;
    return t.s8;
}

// hw trig: sin/cos of x (radians) via v_sin/v_cos (revolutions + fract).
// fp32 fract-reduction == the reference's own fp32 precision; bf16-safe.
__device__ __forceinline__ float hsin(float rev) {
    return __builtin_amdgcn_sinf(__builtin_amdgcn_fractf(rev));
}
__device__ __forceinline__ float hcos(float rev) {
    return __builtin_amdgcn_cosf(__builtin_amdgcn_fractf(rev));
}

// ---------------------------------------------------------------------------
// Weight prep (UNCHANGED): bf16 fragments in MFMA order.
//   dst elem = base + ((ct*KS + ks)*64 + lane)*8 + j,  n = ct*32+ls,
//   k = ks*16 + hi*8 + j.  Regions: L0 @0 (KS=4), L1 @16384, L2 @81920,
//   Wc1 @147456 (all KS=16).
// ---------------------------------------------------------------------------
__global__ __launch_bounds__(256) void prep_weights(
    const float* __restrict__ W0, const float* __restrict__ W1,
    const float* __restrict__ W2, const float* __restrict__ Wc1,
    unsigned short* __restrict__ out)
{
    int i = blockIdx.x * 256 + threadIdx.x;
    if (i >= 180224) return;
    float val;
    if (i < 16384) {
        int j = i & 7, l = (i >> 3) & 63, q = i >> 9;
        int ks = q & 3, ct = q >> 2, ls = l & 31, hi = l >> 5;
        int n = ct * 32 + ls, k = ks * 16 + hi * 8 + j;
        val = (k < 63) ? W0[k * 256 + n] : 0.f;
    } else if (i < 81920) {
        int e = i - 16384;
        int j = e & 7, l = (e >> 3) & 63, q = e >> 9;
        int ks = q & 15, ct = q >> 4, ls = l & 31, hi = l >> 5;
        int n = ct * 32 + ls, k = ks * 16 + hi * 8 + j;
        val = W1[k * 256 + n];
    } else if (i < 147456) {
        int e = i - 81920;
        int j = e & 7, l = (e >> 3) & 63, q = e >> 9;
        int ks = q & 15, ct = q >> 4, ls = l & 31, hi = l >> 5;
        int n = ct * 32 + ls, k = ks * 16 + hi * 8 + j;
        val = W2[k * 256 + n];
    } else {
        int e = i - 147456;
        int j = e & 7, l = (e >> 3) & 63, q = e >> 9;
        int ks = q & 15, ct = q >> 4, ls = l & 31, hi = l >> 5;
        int n = ct * 32 + ls, k = ks * 16 + hi * 8 + j;
        val = Wc1[k * 128 + n];
    }
    out[i] = f2bf(val);
}

// Per-tile epilogue (identical math to green rounds 6/9/10/12).
template <bool DO_SIGMA, bool DO_PACK, bool DO_COLOR>
__device__ __forceinline__ void epilog(
    const f32x16& acc, int ct,
    const float* __restrict__ wsv, const float* __restrict__ wc2R,
    int hi, short8* __restrict__ Bout,
    float& sp, float& c0, float& c1, float& c2)
{
    float rr[16];
    #pragma unroll
    for (int i = 0; i < 16; ++i) rr[i] = fmaxf(acc[i], 0.f);
    if constexpr (DO_SIGMA) {
        #pragma unroll
        for (int g = 0; g < 4; ++g) {
            f32x4 wv = *(const f32x4*)&wsv[ct * 32 + 4 * hi + 8 * g];
            sp = fmaf(rr[4*g+0], wv[0], sp);
            sp = fmaf(rr[4*g+1], wv[1], sp);
            sp = fmaf(rr[4*g+2], wv[2], sp);
            sp = fmaf(rr[4*g+3], wv[3], sp);
        }
    }
    if constexpr (DO_COLOR) {
        #pragma unroll
        for (int g = 0; g < 4; ++g) {
            int nb = ct * 32 + 4 * hi + 8 * g;
            f32x4 w0 = *(const f32x4*)&wc2R[0 * 128 + nb];
            f32x4 w1 = *(const f32x4*)&wc2R[1 * 128 + nb];
            f32x4 w2 = *(const f32x4*)&wc2R[2 * 128 + nb];
            #pragma unroll
            for (int i = 0; i < 4; ++i) {
                c0 = fmaf(rr[4*g+i], w0[i], c0);
                c1 = fmaf(rr[4*g+i], w1[i], c1);
                c2 = fmaf(rr[4*g+i], w2[i], c2);
            }
        }
    }
    if constexpr (DO_PACK) {
        Bout[2*ct+0] = pack_half(rr[0], rr[1], rr[2],  rr[3],
                                 rr[4], rr[5], rr[6],  rr[7]);
        Bout[2*ct+1] = pack_half(rr[8], rr[9], rr[10], rr[11],
                                 rr[12], rr[13], rr[14], rr[15]);
    }
}

// One K=256 layer; rolling 4-fragment window + per-tile RAW s_barrier.
// The barrier is pure wave-alignment (L1 sharing) — there is NO LDS
// dependency in this loop, so we use __builtin_amdgcn_s_barrier() WITHOUT
// the __syncthreads() vmcnt(0) drain: the prefetch window's global loads
// stay in flight across the barrier (AITER-style counted vmcnt).
template <int NT, bool DO_SIGMA, bool DO_PACK, bool DO_COLOR>
__device__ __forceinline__ void mlp_layer(
    const unsigned short* __restrict__ wbase,
    const float* __restrict__ biasv,
    const float* __restrict__ wsv,
    const float* __restrict__ wc2R,
    int lane, int hi,
    const short8 (&Bin)[16], short8* __restrict__ Bout,
    float& sp, float& c0, float& c1, float& c2)
{
    const short8* __restrict__ w = (const short8*)wbase + lane;
    short8 A[4], B4[4];
    #pragma unroll
    for (int j = 0; j < 4; ++j) A[j] = w[j * 64];            // tile0 ks0-3
    #pragma unroll
    for (int ct = 0; ct < NT; ++ct) {
        f32x16 acc;
        #pragma unroll
        for (int g = 0; g < 4; ++g) {
            f32x4 bv = *(const f32x4*)&biasv[ct * 32 + 4 * hi + 8 * g];
            acc[4*g+0]=bv[0]; acc[4*g+1]=bv[1]; acc[4*g+2]=bv[2]; acc[4*g+3]=bv[3];
        }
        #pragma unroll
        for (int j = 0; j < 4; ++j) B4[j] = w[(ct * 16 + 4 + j) * 64];
        #pragma unroll
        for (int j = 0; j < 4; ++j) acc = MFMA32(A[j], Bin[j], acc);
        #pragma unroll
        for (int j = 0; j < 4; ++j) A[j] = w[(ct * 16 + 8 + j) * 64];
        #pragma unroll
        for (int j = 0; j < 4; ++j) acc = MFMA32(B4[j], Bin[4 + j], acc);
        #pragma unroll
        for (int j = 0; j < 4; ++j) B4[j] = w[(ct * 16 + 12 + j) * 64];
        #pragma unroll
        for (int j = 0; j < 4; ++j) acc = MFMA32(A[j], Bin[8 + j], acc);
        if (ct + 1 < NT) {
            #pragma unroll
            for (int j = 0; j < 4; ++j) A[j] = w[((ct + 1) * 16 + j) * 64];
        }
        #pragma unroll
        for (int j = 0; j < 4; ++j) acc = MFMA32(B4[j], Bin[12 + j], acc);
        epilog<DO_SIGMA, DO_PACK, DO_COLOR>(acc, ct, wsv, wc2R, hi, Bout,
                                            sp, c0, c1, c2);
        __builtin_amdgcn_s_barrier();   // align waves; loads stay in flight
    }
}

// ---------------------------------------------------------------------------
// Fused NeRF: 1 block = 1 ray, 256 threads = 4 waves, wave = 32 samples.
// Acts in registers; weights direct from global (L1/L2).
// ---------------------------------------------------------------------------
__global__ __launch_bounds__(256, 2) void nerf_kernel(
    const float* __restrict__ ray, const float* __restrict__ t,
    const float* __restrict__ b0g, const float* __restrict__ b1g,
    const float* __restrict__ b2g,
    const float* __restrict__ Wsg, const float* __restrict__ bsg,
    const float* __restrict__ Wc1g, const float* __restrict__ bc1g,
    const float* __restrict__ Wc2g, const float* __restrict__ bc2g,
    const unsigned short* __restrict__ wt,
    float* __restrict__ rgb_out, float* __restrict__ wi_out)
{
    __shared__ __align__(16) unsigned char s_xe[128 * 128];  // 16 KB posenc
    __shared__ __align__(16) float s_bias[896];  // b0|b1|b2|decont
    __shared__ __align__(16) float s_ws[256];
    __shared__ __align__(16) float s_wc2R[384];  // [c][128]
    __shared__ float s_sigma[128];
    __shared__ float s_color[384];
    __shared__ float s_de[27];
    __shared__ float s_od[6];
    __shared__ float s_t[129];
    __shared__ float s_ts[129];
    __shared__ float s_sdt[128];
    __shared__ float s_cum[128];
    __shared__ float s_wi[128];

    const int tid  = threadIdx.x;
    const int wv   = tid >> 6;
    const int lane = tid & 63;
    const int r    = blockIdx.x;
    const int ls   = lane & 31;
    const int hi   = lane >> 5;
    const int row  = wv * 32 + ls;      // this wave-lane's sample
    const int sw   = (ls & 7) << 4;

    if (tid < 6) s_od[tid] = ray[r * 6 + tid];
    __syncthreads();
    const float d0 = s_od[3], d1 = s_od[4], d2 = s_od[5];

    // ---- fills: biases, head weights, de, t ----
    s_bias[tid] = b0g[tid];
    s_bias[256 + tid] = b1g[tid];
    s_bias[512 + tid] = b2g[tid];
    s_ws[tid] = Wsg[tid];
    for (int i = tid; i < 384; i += 256) {
        int c = i >> 7, n = i & 127;
        s_wc2R[i] = Wc2g[n * 3 + c];
    }
    if (tid < 129) s_t[tid] = t[r * 129 + tid];
    if (tid < 27) {
        int f = tid; float v;
        if (f < 3) v = (f == 0) ? d0 : ((f == 1) ? d1 : d2);
        else {
            int q = f - 3, l = q / 6, rm = q % 6, c = rm % 3;
            float dc = (c == 0) ? d0 : ((c == 1) ? d1 : d2);
            float a = dc * (float)(1 << l) * 0.15915494309189535f;
            v = (rm < 3) ? hsin(a) : hcos(a);
        }
        s_de[f] = v;
    }
    __syncthreads();

    // ---- posenc(x,10) into s_xe (rows=sample, 64 bf16, XOR-swizzled) ------
    // hw v_sin/v_cos per level (revolutions, fract-reduced): no libcalls.
    {
        const int p = tid & 127;
        const int psw = (p & 7) << 4;
        unsigned char* xp = s_xe + p * 128;
        float tv = t[r * 129 + 1 + p];
        if (tid < 128) {
            #pragma unroll
            for (int cgi = 0; cgi < 2; ++cgi) {
                float x = s_od[cgi] + tv * s_od[cgi + 3];
                *(unsigned short*)(xp + ((2 * cgi) ^ psw)) = f2bf(x);
                float r0 = x * 0.15915494309189535f;
                #pragma unroll
                for (int l = 0; l < 10; ++l) {
                    float rv = r0 * (float)(1 << l);
                    *(unsigned short*)(xp + ((2 * (3 + 6 * l + cgi)) ^ psw)) = f2bf(hsin(rv));
                    *(unsigned short*)(xp + ((2 * (6 + 6 * l + cgi)) ^ psw)) = f2bf(hcos(rv));
                }
            }
        } else {
            float x = s_od[2] + tv * s_od[5];
            *(unsigned short*)(xp + (4 ^ psw)) = f2bf(x);
            float r0 = x * 0.15915494309189535f;
            #pragma unroll
            for (int l = 0; l < 10; ++l) {
                float rv = r0 * (float)(1 << l);
                *(unsigned short*)(xp + ((2 * (5 + 6 * l)) ^ psw)) = f2bf(hsin(rv));
                *(unsigned short*)(xp + ((2 * (8 + 6 * l)) ^ psw)) = f2bf(hcos(rv));
            }
            *(unsigned short*)(xp + (126 ^ psw)) = 0;
            // decont[j] = bc1[j] + sum_k de[k]*Wc1[256+k][j]
            float acc = bc1g[p];
            for (int k = 0; k < 27; ++k)
                acc = fmaf(s_de[k], Wc1g[(256 + k) * 128 + p], acc);
            s_bias[768 + p] = acc;
        }
    }
    __syncthreads();

    // ======================= MLP ===========================================
    short8 BA[16], BB[16];
    float sp = 0.f, c0 = 0.f, c1 = 0.f, c2 = 0.f;

    // Layer 0 (K=64): B from s_xe, 8 tiles, 4-frag ping-pong prefetch -> BA
    {
        short8 BX[4];
        #pragma unroll
        for (int ks = 0; ks < 4; ++ks)
            BX[ks] = *(const short8*)(s_xe + row * 128 + ((32 * ks + 16 * hi) ^ sw));
        const short8* __restrict__ w0 = (const short8*)wt + lane;
        short8 Q0[4], Q1[4];
        #pragma unroll
        for (int j = 0; j < 4; ++j) Q0[j] = w0[j * 64];
        #pragma unroll
        for (int ct = 0; ct < 8; ++ct) {
            if (ct + 1 < 8) {
                #pragma unroll
                for (int j = 0; j < 4; ++j)
                    Q1[j] = w0[((ct + 1) * 4 + j) * 64];
            }
            f32x16 acc;
            #pragma unroll
            for (int g = 0; g < 4; ++g) {
                f32x4 bv = *(const f32x4*)&s_bias[ct * 32 + 4 * hi + 8 * g];
                acc[4*g+0]=bv[0]; acc[4*g+1]=bv[1]; acc[4*g+2]=bv[2]; acc[4*g+3]=bv[3];
            }
            #pragma unroll
            for (int j = 0; j < 4; ++j) acc = MFMA32(Q0[j], BX[j], acc);
            epilog<false, true, false>(acc, ct, nullptr, nullptr, hi, BA,
                                       sp, c0, c1, c2);
            #pragma unroll
            for (int j = 0; j < 4; ++j) Q0[j] = Q1[j];   // renamed, unrolled
        }
    }

    // Layer 1: BA -> BB
    mlp_layer<8, false, true, false>(wt + 16384, s_bias + 256, nullptr, nullptr,
                                     lane, hi, BA, BB, sp, c0, c1, c2);
    // Layer 2: BB -> BA, sigma partial accumulated
    mlp_layer<8, true, true, false>(wt + 81920, s_bias + 512, s_ws, nullptr,
                                    lane, hi, BB, BA, sp, c0, c1, c2);
    // sigma finalize
    sp += __shfl_xor(sp, 32);
    if (lane < 32) {
        float x = sp + bsg[0];
        s_sigma[row] = fmaxf(x, 0.f) + log1pf(expf(-fabsf(x)));
    }
    // Wc1 (128 cols): BA -> color partials
    mlp_layer<4, false, false, true>(wt + 147456, s_bias + 768, nullptr, s_wc2R,
                                     lane, hi, BA, BB, sp, c0, c1, c2);
    c0 += __shfl_xor(c0, 32);
    c1 += __shfl_xor(c1, 32);
    c2 += __shfl_xor(c2, 32);
    if (lane < 32) {
        s_color[row * 3 + 0] = 1.f / (1.f + expf(-(c0 + bc2g[0])));
        s_color[row * 3 + 1] = 1.f / (1.f + expf(-(c1 + bc2g[1])));
        s_color[row * 3 + 2] = 1.f / (1.f + expf(-(c2 + bc2g[2])));
    }
    __syncthreads();

    // ======================= render (sort/scan/composite) ==================
    if (tid < 129) {
        float v = s_t[tid];
        int rank = 0;
        for (int j = 0; j < 129; ++j) {
            float u = s_t[j];
            rank += (u < v) || (u == v && j < tid);
        }
        s_ts[rank] = v;
    }
    __syncthreads();
    if (tid < 128) {
        float dt = s_ts[tid + 1] - s_ts[tid];
        float sd = s_sigma[tid] * dt;
        s_sdt[tid] = sd;
        s_cum[tid] = sd;
    }
    __syncthreads();
    for (int off = 1; off < 128; off <<= 1) {
        float add = (tid < 128 && tid >= off) ? s_cum[tid - off] : 0.f;
        __syncthreads();
        if (tid < 128) s_cum[tid] += add;
        __syncthreads();
    }
    if (tid < 128) {
        float Ti = (tid == 0) ? 1.f : expf(-s_cum[tid - 1]);
        float alpha = 1.f - expf(-s_sdt[tid]);
        float w = Ti * alpha;
        s_wi[tid] = w;
        wi_out[r * 128 + tid] = w;
    }
    __syncthreads();
    if (tid < 3) {
        float acc = 0.f;
        for (int i = 0; i < 128; ++i)
            acc = fmaf(s_wi[i], s_color[i * 3 + tid], acc);
        rgb_out[r * 3 + tid] = acc;
    }
}

extern "C" void kernel_launch(void* const* d_in, const int* in_sizes, int n_in,
                              void* d_out, int out_size, void* d_ws, size_t ws_size,
                              hipStream_t stream)
{
    const float* ray = (const float*)d_in[0];
    const float* t   = (const float*)d_in[1];
    const float* W0  = (const float*)d_in[2];
    const float* b0  = (const float*)d_in[3];
    const float* W1  = (const float*)d_in[4];
    const float* b1  = (const float*)d_in[5];
    const float* W2  = (const float*)d_in[6];
    const float* b2  = (const float*)d_in[7];
    const float* Ws  = (const float*)d_in[8];
    const float* bs  = (const float*)d_in[9];
    const float* Wc1 = (const float*)d_in[10];
    const float* bc1 = (const float*)d_in[11];
    const float* Wc2 = (const float*)d_in[12];
    const float* bc2 = (const float*)d_in[13];

    unsigned short* wt = (unsigned short*)d_ws;   // 360448 B fragment image
    float* rgb_out = (float*)d_out;               // R*3
    float* wi_out  = rgb_out + R_ * 3;            // R*128

    hipLaunchKernelGGL(prep_weights, dim3(704), dim3(256), 0, stream,
                       W0, W1, W2, Wc1, wt);
    hipLaunchKernelGGL(nerf_kernel, dim3(R_), dim3(256), 0, stream,
                       ray, t, b0, b1, b2, Ws, bs, Wc1, bc1, Wc2, bc2,
                       wt, rgb_out, wi_out);
}